// Round 8
// baseline (501.304 us; speedup 1.0000x reference)
//
// v5 = v2 core (per-wave LDS B staging, counted vmcnt) minus measured warts:
//      2-deep A prefetch (was 8-deep, spilled), Hm folded via negated Wcomb
//      (no hmp regs), f32-h direct A (no h-cvt dispatch), precomputed row
//      scales (no index/t chases), 1 loss atomic per block.
#include <hip/hip_runtime.h>
#include <math.h>

#define NTHREADS 256
#define EPSC 1e-6f
#define NPL 3   // node slots per lane in pos branch: covers up to 192 nodes/graph

typedef short bf16x8 __attribute__((ext_vector_type(8)));
typedef float f32x4  __attribute__((ext_vector_type(4)));

#define GLDS(srcp, dstp) __builtin_amdgcn_global_load_lds( \
    (const __attribute__((address_space(1))) void*)(srcp), \
    (__attribute__((address_space(3))) void*)(dstp), 16, 0, 0)

// ---------------------------------------------------------------------------
// helpers
// ---------------------------------------------------------------------------
__device__ __forceinline__ ushort f2bf(float x) {   // RNE float->bf16
  union { float f; unsigned u; } v; v.f = x;
  unsigned r = v.u + 0x7FFFu + ((v.u >> 16) & 1u);
  return (ushort)(r >> 16);
}
__device__ __forceinline__ float bf2f(ushort x) {
  union { unsigned u; float f; } v; v.u = ((unsigned)x) << 16;
  return v.f;
}
__device__ __forceinline__ bf16x8 pack8(float4 a, float4 b) {
  bf16x8 r;
  r[0]=(short)f2bf(a.x); r[1]=(short)f2bf(a.y); r[2]=(short)f2bf(a.z); r[3]=(short)f2bf(a.w);
  r[4]=(short)f2bf(b.x); r[5]=(short)f2bf(b.y); r[6]=(short)f2bf(b.z); r[7]=(short)f2bf(b.w);
  return r;
}
__device__ __forceinline__ float tanh_fast(float x) {
  float xc = fminf(fmaxf(x, -15.f), 15.f);
  float e = __expf(2.f * xc);
  return (e - 1.f) / (e + 1.f);
}

__device__ __forceinline__ void inv3x3(const float m[9], float o[9]) {
  float a=m[0],b=m[1],c=m[2],d=m[3],e=m[4],f=m[5],g=m[6],h=m[7],i=m[8];
  float det = a*e*i + b*f*g + d*h*c - g*e*c - a*h*f - d*b*i;
  float r = 1.0f/det;
  o[0]=(e*i-f*h)*r; o[1]=(c*h-b*i)*r; o[2]=(b*f-c*e)*r;
  o[3]=(f*g-d*i)*r; o[4]=(a*i-c*g)*r; o[5]=(c*d-a*f)*r;
  o[6]=(d*h-e*g)*r; o[7]=(b*g-a*h)*r; o[8]=(a*e-b*d)*r;
}

__device__ __forceinline__ float wred(float v) {
#pragma unroll
  for (int o = 32; o > 0; o >>= 1) v += __shfl_xor(v, o, 64);
  return v;
}

// ---------------------------------------------------------------------------
// Fused pos branch: one wave per graph (verified absmax 0.0)
// ---------------------------------------------------------------------------
__global__ __launch_bounds__(64) void pos_branch_v5(
    int N, const float* __restrict__ pos, const float* __restrict__ epsp,
    const int* __restrict__ index, const float* __restrict__ t,
    const float* __restrict__ gpp, double* __restrict__ lossp)
{
  const int b = blockIdx.x;
  const int lane = threadIdx.x;

  int lo = 0, hi = N;
  while (lo < hi) { int mid = (lo + hi) >> 1; if (index[mid] < b) lo = mid + 1; else hi = mid; }
  const int start = lo;
  hi = N;
  while (lo < hi) { int mid = (lo + hi) >> 1; if (index[mid] < b + 1) lo = mid + 1; else hi = mid; }
  const int end = lo;
  const int cnt = end - start;
  const float fn = (float)cnt, rc = 1.0f / fn;

  const float tn  = t[b];
  const float a1  = 0.2f + 0.8f*tn, b1 = 0.1f*tn;
  const float omt = 1.0f - tn;
  const float sp  = log1pf(expf(gpp[0]));
  const float gp  = 0.1f + sp*tn;
  const float hg  = 0.5f*gp*gp;
  const float rgp = 1.0f/gp;
  const float pscale = 1.0f - 0.9f*omt;

  float iU[NPL][9], yv[NPL][3], wv[NPL][3], dwv[NPL][3], pv[NPL][3];
  float Vs[9] = {0}, wb[3] = {0}, dwb[3] = {0}, yb[3] = {0};
#pragma unroll
  for (int k = 0; k < NPL; ++k) {
    const int n = start + k*64 + lane;
    if (n < end) {
      const float px = pos[3*(size_t)n+0], py = pos[3*(size_t)n+1], pz = pos[3*(size_t)n+2];
      const float ex = epsp[3*(size_t)n+0], ey = epsp[3*(size_t)n+1], ez = epsp[3*(size_t)n+2];
      pv[k][0]=px; pv[k][1]=py; pv[k][2]=pz;
      const float pn = sqrtf(px*px+py*py+pz*pz) + EPSC;
      const float nx = px/pn, ny = py/pn, nz = pz/pn;
      const float nd = nx*ex + ny*ey + nz*ez;
      wv[k][0]=a1*ex + b1*nd*nx; wv[k][1]=a1*ey + b1*nd*ny; wv[k][2]=a1*ez + b1*nd*nz;
      dwv[k][0]=0.8f*ex + 0.1f*nd*nx; dwv[k][1]=0.8f*ey + 0.1f*nd*ny; dwv[k][2]=0.8f*ez + 0.1f*nd*nz;
      const float U[9] = { a1 + b1*nx*nx, b1*nx*ny,      b1*nx*nz,
                           b1*ny*nx,      a1 + b1*ny*ny, b1*ny*nz,
                           b1*nz*nx,      b1*nz*ny,      a1 + b1*nz*nz };
      inv3x3(U, iU[k]);
      yv[k][0] = iU[k][0]*ex + iU[k][3]*ey + iU[k][6]*ez;
      yv[k][1] = iU[k][1]*ex + iU[k][4]*ey + iU[k][7]*ez;
      yv[k][2] = iU[k][2]*ex + iU[k][5]*ey + iU[k][8]*ez;
#pragma unroll
      for (int j = 0; j < 9; ++j) Vs[j] += iU[k][j];
#pragma unroll
      for (int j = 0; j < 3; ++j) { wb[j]+=wv[k][j]; dwb[j]+=dwv[k][j]; yb[j]+=yv[k][j]; }
    }
  }
#pragma unroll
  for (int j = 0; j < 9; ++j) Vs[j] = wred(Vs[j]);
#pragma unroll
  for (int j = 0; j < 3; ++j) { wb[j]=wred(wb[j]); dwb[j]=wred(dwb[j]); yb[j]=wred(yb[j]); }

  float iV[9]; inv3x3(Vs, iV);
  float wm[3], dwm[3], u1[3], s1m[3];
#pragma unroll
  for (int i = 0; i < 3; ++i) { wm[i] = wb[i]*rc; dwm[i] = dwb[i]*rc; }
#pragma unroll
  for (int i = 0; i < 3; ++i) u1[i] = iV[0*3+i]*yb[0] + iV[1*3+i]*yb[1] + iV[2*3+i]*yb[2];
#pragma unroll
  for (int i = 0; i < 3; ++i) {
    const float csy = Vs[0*3+i]*u1[0] + Vs[1*3+i]*u1[1] + Vs[2*3+i]*u1[2] - fn*u1[i];
    s1m[i] = (csy - yb[i]) * rc;
  }

  float tg[NPL][3], zp[NPL][3], iU2[NPL][9], qv[NPL][3];
  float Vs2[9] = {0}, qs[3] = {0}, ps[3] = {0};
#pragma unroll
  for (int k = 0; k < NPL; ++k) {
    const int n = start + k*64 + lane;
    if (n < end) {
#pragma unroll
      for (int i = 0; i < 3; ++i) {
        const float c1 = iU[k][0*3+i]*u1[0] + iU[k][1*3+i]*u1[1] + iU[k][2*3+i]*u1[2] - u1[i];
        const float score1 = c1 - yv[k][i] - s1m[i];
        tg[k][i] = -pv[k][i] + dwv[k][i] - dwm[i] - hg*score1;
        zp[k][i] = pv[k][i]*omt + wv[k][i] - wm[i];
      }
      const float rx = 0.9f*zp[k][0], ry = 0.9f*zp[k][1], rz = 0.9f*zp[k][2];
      const float rn = sqrtf(rx*rx+ry*ry+rz*rz) + EPSC;
      const float nx = rx/rn, ny = ry/rn, nz = rz/rn;
      const float U2[9] = { a1 + b1*nx*nx, b1*nx*ny,      b1*nx*nz,
                            b1*ny*nx,      a1 + b1*ny*ny, b1*ny*nz,
                            b1*nz*nx,      b1*nz*ny,      a1 + b1*nz*nz };
      inv3x3(U2, iU2[k]);
      float prel[3];
#pragma unroll
      for (int i = 0; i < 3; ++i) prel[i] = zp[k][i]*pscale;
#pragma unroll
      for (int i = 0; i < 3; ++i)
        qv[k][i] = iU2[k][i*3+0]*prel[0] + iU2[k][i*3+1]*prel[1] + iU2[k][i*3+2]*prel[2];
#pragma unroll
      for (int j = 0; j < 9; ++j) Vs2[j] += iU2[k][j];
#pragma unroll
      for (int j = 0; j < 3; ++j) { qs[j] += qv[k][j]; ps[j] += prel[j]; }
    }
  }
#pragma unroll
  for (int j = 0; j < 9; ++j) Vs2[j] = wred(Vs2[j]);
#pragma unroll
  for (int j = 0; j < 3; ++j) { qs[j] = wred(qs[j]); ps[j] = wred(ps[j]); }

  float iV2[9]; inv3x3(Vs2, iV2);
  float cb2[3];
#pragma unroll
  for (int i = 0; i < 3; ++i)
    cb2[i] = iV2[i*3+0]*(qs[0]-ps[0]) + iV2[i*3+1]*(qs[1]-ps[1]) + iV2[i*3+2]*(qs[2]-ps[2]);

  float y2v[NPL][3], dw2v[NPL][3];
  float yb2[3] = {0}, dwb2[3] = {0};
#pragma unroll
  for (int k = 0; k < NPL; ++k) {
    const int n = start + k*64 + lane;
    if (n < end) {
      float e[3];
#pragma unroll
      for (int i = 0; i < 3; ++i)
        e[i] = qv[k][i] - (iU2[k][i*3+0]*cb2[0] + iU2[k][i*3+1]*cb2[1] + iU2[k][i*3+2]*cb2[2]);
#pragma unroll
      for (int i = 0; i < 3; ++i)
        y2v[k][i] = iU2[k][0*3+i]*e[0] + iU2[k][1*3+i]*e[1] + iU2[k][2*3+i]*e[2];
      const float rx = 0.9f*zp[k][0], ry = 0.9f*zp[k][1], rz = 0.9f*zp[k][2];
      const float rn = sqrtf(rx*rx+ry*ry+rz*rz) + EPSC;
      const float nx = rx/rn, ny = ry/rn, nz = rz/rn;
      const float nd = nx*e[0] + ny*e[1] + nz*e[2];
      dw2v[k][0] = 0.8f*e[0] + 0.1f*nd*nx;
      dw2v[k][1] = 0.8f*e[1] + 0.1f*nd*ny;
      dw2v[k][2] = 0.8f*e[2] + 0.1f*nd*nz;
#pragma unroll
      for (int j = 0; j < 3; ++j) { yb2[j] += y2v[k][j]; dwb2[j] += dw2v[k][j]; }
    }
  }
#pragma unroll
  for (int j = 0; j < 3; ++j) { yb2[j] = wred(yb2[j]); dwb2[j] = wred(dwb2[j]); }

  float u2[3], s2m[3], dw2m[3];
#pragma unroll
  for (int i = 0; i < 3; ++i) u2[i] = iV2[0*3+i]*yb2[0] + iV2[1*3+i]*yb2[1] + iV2[2*3+i]*yb2[2];
#pragma unroll
  for (int i = 0; i < 3; ++i) {
    const float csy = Vs2[0*3+i]*u2[0] + Vs2[1*3+i]*u2[1] + Vs2[2*3+i]*u2[2] - fn*u2[i];
    s2m[i] = (csy - yb2[i]) * rc;
    dw2m[i] = dwb2[i] * rc;
  }

  float acc = 0.0f;
#pragma unroll
  for (int k = 0; k < NPL; ++k) {
    const int n = start + k*64 + lane;
    if (n < end) {
#pragma unroll
      for (int i = 0; i < 3; ++i) {
        const float c2 = iU2[k][0*3+i]*u2[0] + iU2[k][1*3+i]*u2[1] + iU2[k][2*3+i]*u2[2] - u2[i];
        const float score2 = c2 - y2v[k][i] - s2m[i];
        const float dz2 = -0.9f*zp[k][i] + dw2v[k][i] - dw2m[i];
        const float apx = dz2 - hg*score2;
        const float d = (apx - tg[k][i]) * rgp;
        acc += d*d;
      }
    }
  }
  acc = wred(acc);
  if (lane == 0) atomicAdd(lossp, (double)acc);
}

// ---------------------------------------------------------------------------
// prep: W_r2 cvt (128) | W_mu^T (64) | W_r1^T (128) | row scales (rest)
//   zsc[r] = (1-tn, 0.1+0.9tn);  lsc[r] = fac/gh   (same fp exprs as before
//   -> bit-identical; removes index/t chases from the hot kernel)
// ---------------------------------------------------------------------------
__global__ __launch_bounds__(NTHREADS) void prep_v5(
    const float4* __restrict__ wr2, ushort4* __restrict__ wr2b, int n4w,
    const float* __restrict__ wmu, ushort* __restrict__ wmut,
    const float* __restrict__ wr1, ushort* __restrict__ wr1t,
    const float* __restrict__ t, const int* __restrict__ index,
    const float* __restrict__ gph,
    float2* __restrict__ zsc, float* __restrict__ lsc, int Nn)
{
  __shared__ float ts[32][33];
  const int bid = blockIdx.x;
  if (bid < 128) {
    const int i = bid*NTHREADS + threadIdx.x;
    if (i < n4w) {
      float4 v = wr2[i];
      wr2b[i] = make_ushort4(f2bf(v.x), f2bf(v.y), f2bf(v.z), f2bf(v.w));
    }
  } else if (bid < 192) {           // W_mu^T: in [256][256] -> out[n][k]
    const int vb = bid - 128;
    const int nb = (vb & 7)*32, kb = (vb >> 3)*32;
    const int tx = threadIdx.x & 31, ty = threadIdx.x >> 5;
#pragma unroll
    for (int r = 0; r < 4; ++r)
      ts[ty + r*8][tx] = wmu[(size_t)(kb + ty + r*8)*256 + nb + tx];
    __syncthreads();
#pragma unroll
    for (int r = 0; r < 4; ++r)
      wmut[(size_t)(nb + ty + r*8)*256 + kb + tx] = f2bf(ts[tx][ty + r*8]);
  } else if (bid < 320) {           // W_r1^T: in [256][512] -> out[n][k], n<512
    const int vb = bid - 192;
    const int nb = (vb & 15)*32, kb = (vb >> 4)*32;
    const int tx = threadIdx.x & 31, ty = threadIdx.x >> 5;
#pragma unroll
    for (int r = 0; r < 4; ++r)
      ts[ty + r*8][tx] = wr1[(size_t)(kb + ty + r*8)*512 + nb + tx];
    __syncthreads();
#pragma unroll
    for (int r = 0; r < 4; ++r)
      wr1t[(size_t)(nb + ty + r*8)*256 + kb + tx] = f2bf(ts[tx][ty + r*8]);
  } else {                          // per-row scales
    const int r = (bid - 320)*NTHREADS + threadIdx.x;
    if (r < Nn) {
      const float tn = t[index[r]];
      zsc[r] = make_float2(1.0f - tn, 0.1f + 0.9f*tn);
      const float sp  = log1pf(expf(gph[0]));
      const float gh  = 0.1f + sp*tn;
      const float sig = 0.1f + 0.9f*tn;
      const float fac = 1.0f + (0.9f + 0.5f*gh*gh/sig)*(1.0f - tn)/sig;
      lsc[r] = fac/gh;
    }
  }
}

// ---------------------------------------------------------------------------
// Wcomb^T = -(W_r2 @ W_mu)^T  (NEGATED: h kernel accumulates Hm - T1@Wcomb
// directly on the GEMM1 accumulator). Transposed bf16 store.
// ---------------------------------------------------------------------------
__global__ __launch_bounds__(256) void wcomb_gemm_v5(
    const ushort* __restrict__ A, const ushort* __restrict__ Bt,
    int K, int Nn, int Mvalid, ushort* __restrict__ OutB)
{
  __shared__ __align__(16) ushort As[128*32];
  __shared__ __align__(16) ushort Bs[128*32];
  const int tid = threadIdx.x;
  const int row0 = blockIdx.y*128, col0 = blockIdx.x*128;
  const int wave = tid >> 6, lane = tid & 63;
  const int wm = (wave & 1)*64, wn = (wave >> 1)*64;
  const int lm = lane & 15, lq = lane >> 4;

  f32x4 acc[4][4];
#pragma unroll
  for (int i = 0; i < 4; ++i)
#pragma unroll
    for (int j = 0; j < 4; ++j) { acc[i][j][0]=0.f; acc[i][j][1]=0.f; acc[i][j][2]=0.f; acc[i][j][3]=0.f; }

  const int c0 = tid, c1 = tid + 256;
  const int r0a = c0 >> 2, k0a = (c0 & 3) << 3;
  const int r1a = c1 >> 2, k1a = (c1 & 3) << 3;

  for (int k0 = 0; k0 < K; k0 += 32) {
    __syncthreads();
    GLDS(A  + (size_t)(row0 + r0a)*K + k0 + k0a, As + c0*8);
    GLDS(A  + (size_t)(row0 + r1a)*K + k0 + k1a, As + c1*8);
    GLDS(Bt + (size_t)(col0 + r0a)*K + k0 + k0a, Bs + c0*8);
    GLDS(Bt + (size_t)(col0 + r1a)*K + k0 + k1a, Bs + c1*8);
    __syncthreads();

    bf16x8 af[4], bfr[4];
#pragma unroll
    for (int i = 0; i < 4; ++i)
      af[i] = *(const bf16x8*)&As[(wm + i*16 + lm)*32 + lq*8];
#pragma unroll
    for (int j = 0; j < 4; ++j)
      bfr[j] = *(const bf16x8*)&Bs[(wn + j*16 + lm)*32 + lq*8];
#pragma unroll
    for (int i = 0; i < 4; ++i)
#pragma unroll
      for (int j = 0; j < 4; ++j)
        acc[i][j] = __builtin_amdgcn_mfma_f32_16x16x32_bf16(af[i], bfr[j], acc[i][j], 0, 0, 0);
  }

#pragma unroll
  for (int i = 0; i < 4; ++i) {
#pragma unroll
    for (int reg = 0; reg < 4; ++reg) {
      const int r = row0 + wm + i*16 + lq*4 + reg;
#pragma unroll
      for (int j = 0; j < 4; ++j) {
        const int cc = col0 + wn + j*16 + lm;
        OutB[(size_t)cc*Mvalid + r] = f2bf(-acc[i][j][reg]);   // NEGATED, transposed
      }
    }
  }
}

// ---------------------------------------------------------------------------
// v5 fused h branch. 64 rows/block, 4 waves (column split).
//   GEMM1: A = f32 h -> in-reg bf16 (2-deep prefetch, vmcnt(12));
//          B = per-wave LDS slice, 2-buf rotation (v2 scheme, vmcnt counted).
//   epi1:  z = acc*zsc.x + zsc.y*eps -> swizzled zs. acc keeps Hm (f32).
//   chunks: GEMM2 (B 2-buf, vmcnt(2)); tanh -> t1s; GEMM3 (B 2-buf, vmcnt(4))
//          accumulating onto acc (Wcomb pre-negated).
//   loss:  d = acc * lsc[r]; LDS block reduce, 1 atomic/block.
// LDS 80K -> 2 blocks/CU. No index/t reads in this kernel at all.
// ---------------------------------------------------------------------------
__global__ __launch_bounds__(256, 2) void h_branch_v5(
    const float* __restrict__ hf, const ushort* __restrict__ wmut,
    const ushort* __restrict__ wr1t, const ushort* __restrict__ wct,
    const float* __restrict__ eps, const float2* __restrict__ zsc,
    const float* __restrict__ lsc,
    int N, double* __restrict__ lossAcc)
{
  __shared__ __align__(16) ushort zs[64*256];     // 32 KB, swizzled
  __shared__ __align__(16) ushort t1s[64*128];    // 16 KB, swizzled
  __shared__ __align__(16) ushort bstg[4*4096];   // 32 KB: per-wave 2x4KB bufs
  __shared__ double redsm[4];

  const int wave = threadIdx.x >> 6, lane = threadIdx.x & 63;
  const int row0 = blockIdx.x * 64;
  const int lm = lane & 15, lq = lane >> 4;
  const int wn  = wave * 64;    // col base within 256 (GEMM1 / loss)
  const int wn2 = wave * 32;    // col base within 128 (T1 chunk)
  ushort* const bsw = bstg + wave*4096;   // [2][2048] ushorts

  // row indices for this thread's A-fragments (clamped; masked in loss)
  int arow[4];
#pragma unroll
  for (int i = 0; i < 4; ++i) {
    int r = row0 + i*16 + lm; if (r >= N) r = N - 1;
    arow[i] = r;
  }

  // ---- GEMM1 prologue: A(0) 8 f32x4 loads + B(0) 4 GLDS  (12 in flight) ----
  float4 aCur[8], aNxt[8];
#pragma unroll
  for (int i = 0; i < 4; ++i) {
    const float4* p = (const float4*)(hf + (size_t)arow[i]*256 + lq*8);
    aCur[2*i] = p[0]; aCur[2*i+1] = p[1];
  }
#pragma unroll
  for (int c = 0; c < 4; ++c) {
    const int ch = c*64 + lane;
    GLDS(wmut + (size_t)(wn + (ch>>2))*256 + ((ch&3)<<3), bsw + ch*8);
  }

  f32x4 acc[4][4];
#pragma unroll
  for (int i = 0; i < 4; ++i)
#pragma unroll
    for (int j = 0; j < 4; ++j) { acc[i][j][0]=0.f; acc[i][j][1]=0.f; acc[i][j][2]=0.f; acc[i][j][3]=0.f; }

#pragma unroll
  for (int k = 0; k < 8; ++k) {
    if (k < 7) {
#pragma unroll
      for (int i = 0; i < 4; ++i) {
        const float4* p = (const float4*)(hf + (size_t)arow[i]*256 + (k+1)*32 + lq*8);
        aNxt[2*i] = p[0]; aNxt[2*i+1] = p[1];
      }
#pragma unroll
      for (int c = 0; c < 4; ++c) {
        const int ch = c*64 + lane;
        GLDS(wmut + (size_t)(wn + (ch>>2))*256 + (k+1)*32 + ((ch&3)<<3),
             bsw + ((k+1)&1)*2048 + ch*8);
      }
      asm volatile("s_waitcnt vmcnt(12)" ::: "memory");   // A(k+1)+B(k+1) fly
    } else {
      asm volatile("s_waitcnt vmcnt(0)" ::: "memory");
    }
    __builtin_amdgcn_sched_barrier(0);

    const ushort* cb = bsw + (k&1)*2048;
    bf16x8 a_[4], b_[4];
#pragma unroll
    for (int i = 0; i < 4; ++i) a_[i] = pack8(aCur[2*i], aCur[2*i+1]);
#pragma unroll
    for (int j = 0; j < 4; ++j)
      b_[j] = *(const bf16x8*)&cb[(j*16 + lm)*32 + lq*8];
#pragma unroll
    for (int i = 0; i < 4; ++i)
#pragma unroll
      for (int j = 0; j < 4; ++j)
        acc[i][j] = __builtin_amdgcn_mfma_f32_16x16x32_bf16(a_[i], b_[j], acc[i][j], 0, 0, 0);

    if (k < 7) {
#pragma unroll
      for (int q = 0; q < 8; ++q) aCur[q] = aNxt[q];   // renamed away by unroll
    }
  }

  // early-stage chunk0 GEMM2 B0 (own 32-col slice of W_r1^T)
#pragma unroll
  for (int c = 0; c < 2; ++c) {
    const int ch = c*64 + lane;
    GLDS(wr1t + (size_t)(wn2 + (ch>>2))*256 + ((ch&3)<<3), bsw + ch*8);
  }

  // ---- epilogue 1: z_h -> swizzled LDS (acc keeps Hm in f32) ----
#pragma unroll
  for (int i = 0; i < 4; ++i) {
#pragma unroll
    for (int reg = 0; reg < 4; ++reg) {
      const int rb = i*16 + lq*4 + reg;
      const int r = row0 + rb;
      const int rcl = (r < N) ? r : (N - 1);
      const float2 sz = zsc[rcl];
#pragma unroll
      for (int j = 0; j < 4; ++j) {
        const int cc = wn + j*16 + lm;
        const float z = acc[i][j][reg]*sz.x + sz.y*eps[(size_t)rcl*256 + cc];
        zs[rb*256 + (cc ^ ((rb & 7) << 3))] = f2bf(z);
      }
    }
  }
  __syncthreads();   // zs visible (drains in-flight staging too)

  // ---- chunk loop ----
  for (int c2 = 0; c2 < 4; ++c2) {
    f32x4 acct[4][2];
#pragma unroll
    for (int i = 0; i < 4; ++i)
#pragma unroll
      for (int j = 0; j < 2; ++j) { acct[i][j][0]=0.f; acct[i][j][1]=0.f; acct[i][j][2]=0.f; acct[i][j][3]=0.f; }

#pragma unroll
    for (int k = 0; k < 8; ++k) {
      if (k < 7) {
#pragma unroll
        for (int c = 0; c < 2; ++c) {
          const int ch = c*64 + lane;
          GLDS(wr1t + (size_t)(c2*128 + wn2 + (ch>>2))*256 + (k+1)*32 + ((ch&3)<<3),
               bsw + ((k+1)&1)*2048 + ch*8);
        }
        asm volatile("s_waitcnt vmcnt(2)" ::: "memory");
      } else {
        asm volatile("s_waitcnt vmcnt(0)" ::: "memory");
      }
      __builtin_amdgcn_sched_barrier(0);

      const ushort* cb = bsw + (k&1)*2048;
      bf16x8 az[4], b_[2];
#pragma unroll
      for (int i = 0; i < 4; ++i) {
        const int r = i*16 + lm;
        const int c = k*32 + lq*8;
        az[i] = *(const bf16x8*)&zs[r*256 + (c ^ ((r & 7) << 3))];
      }
#pragma unroll
      for (int j = 0; j < 2; ++j)
        b_[j] = *(const bf16x8*)&cb[(j*16 + lm)*32 + lq*8];
#pragma unroll
      for (int i = 0; i < 4; ++i)
#pragma unroll
        for (int j = 0; j < 2; ++j)
          acct[i][j] = __builtin_amdgcn_mfma_f32_16x16x32_bf16(az[i], b_[j], acct[i][j], 0, 0, 0);
    }

    // early-stage GEMM3 B0 (own 64-col slice of -Wcomb^T, this chunk)
#pragma unroll
    for (int c = 0; c < 4; ++c) {
      const int ch = c*64 + lane;
      GLDS(wct + (size_t)(wn + (ch>>2))*512 + c2*128 + ((ch&3)<<3), bsw + ch*8);
    }
    __syncthreads();   // barrier_A: all waves past prev-chunk t1s reads

#pragma unroll
    for (int i = 0; i < 4; ++i)
#pragma unroll
      for (int j = 0; j < 2; ++j)
#pragma unroll
        for (int reg = 0; reg < 4; ++reg) {
          const int rb = i*16 + lq*4 + reg;
          const int c = wn2 + j*16 + lm;
          t1s[rb*128 + (c ^ ((rb & 7) << 3))] = f2bf(tanh_fast(acct[i][j][reg]));
        }
    __syncthreads();   // barrier_B: t1s visible

#pragma unroll
    for (int k = 0; k < 4; ++k) {
      if (k < 3) {
#pragma unroll
        for (int c = 0; c < 4; ++c) {
          const int ch = c*64 + lane;
          GLDS(wct + (size_t)(wn + (ch>>2))*512 + c2*128 + (k+1)*32 + ((ch&3)<<3),
               bsw + ((k+1)&1)*2048 + ch*8);
        }
        asm volatile("s_waitcnt vmcnt(4)" ::: "memory");
      } else {
        asm volatile("s_waitcnt vmcnt(0)" ::: "memory");
      }
      __builtin_amdgcn_sched_barrier(0);

      const ushort* cb = bsw + (k&1)*2048;
      bf16x8 at[4], b_[4];
#pragma unroll
      for (int i = 0; i < 4; ++i) {
        const int r = i*16 + lm;
        const int c = k*32 + lq*8;
        at[i] = *(const bf16x8*)&t1s[r*128 + (c ^ ((r & 7) << 3))];
      }
#pragma unroll
      for (int j = 0; j < 4; ++j)
        b_[j] = *(const bf16x8*)&cb[(j*16 + lm)*32 + lq*8];
#pragma unroll
      for (int i = 0; i < 4; ++i)
#pragma unroll
        for (int j = 0; j < 4; ++j)
          acc[i][j] = __builtin_amdgcn_mfma_f32_16x16x32_bf16(at[i], b_[j], acc[i][j], 0, 0, 0);
    }

    if (c2 < 3) {   // early-stage next chunk's GEMM2 B0
#pragma unroll
      for (int c = 0; c < 2; ++c) {
        const int ch = c*64 + lane;
        GLDS(wr1t + (size_t)((c2+1)*128 + wn2 + (ch>>2))*256 + ((ch&3)<<3), bsw + ch*8);
      }
    }
  }

  // ---- loss epilogue: acc already = Hm - T1@Wcomb;  d = acc * lsc[r] ----
  float local = 0.f;
#pragma unroll
  for (int i = 0; i < 4; ++i) {
#pragma unroll
    for (int reg = 0; reg < 4; ++reg) {
      const int r = row0 + i*16 + lq*4 + reg;
      if (r < N) {
        const float sc = lsc[r];
#pragma unroll
        for (int j = 0; j < 4; ++j) {
          const float d = acc[i][j][reg] * sc;
          local += d*d;
        }
      }
    }
  }
  double dv = (double)local;
#pragma unroll
  for (int off = 32; off > 0; off >>= 1) dv += __shfl_down(dv, off, 64);
  if (lane == 0) redsm[wave] = dv;
  __syncthreads();
  if (threadIdx.x == 0)
    atomicAdd(lossAcc, redsm[0] + redsm[1] + redsm[2] + redsm[3]);
}

__global__ void finalize_v5(const double* lossh, const double* lossp,
                            float* out, int N, int DH)
{
  if (threadIdx.x == 0) {
    out[0] = (float)(lossh[0] / ((double)N * (double)DH));
    out[1] = (float)(lossp[0] / ((double)N * 3.0));
  }
}

// ---------------------------------------------------------------------------
extern "C" void kernel_launch(void* const* d_in, const int* in_sizes, int n_in,
                              void* d_out, int out_size, void* d_ws, size_t ws_size,
                              hipStream_t stream) {
  const float* t      = (const float*)d_in[0];
  const float* h      = (const float*)d_in[1];
  const float* pos    = (const float*)d_in[2];
  const float* eps_h  = (const float*)d_in[3];
  const float* eps_p  = (const float*)d_in[4];
  const float* gph    = (const float*)d_in[5];
  const float* gpp    = (const float*)d_in[6];
  const float* W_mu   = (const float*)d_in[7];
  const float* W_r1   = (const float*)d_in[8];
  const float* W_r2   = (const float*)d_in[9];
  const int*   index  = (const int*)d_in[10];
  const int B = in_sizes[0];
  const int N = in_sizes[10];
  const int DH = 256, DH2 = 512;

  char* ws = (char*)d_ws;
  size_t off = 0;
  auto alloc = [&](size_t nbytes) { size_t o = off; off += (nbytes + 255) & ~(size_t)255; return o; };

  size_t o_loss = alloc(16);                             // 2 doubles (zeroed)
  size_t o_wmut = alloc((size_t)DH*DH*2);                // W_mu^T  [256][256]
  size_t o_wr1t = alloc((size_t)DH2*DH*2);               // W_r1^T  [512][256]
  size_t o_wr2b = alloc((size_t)DH2*DH*2);               // W_r2 bf16 [512][256]
  size_t o_wct  = alloc((size_t)DH*DH2*2);               // -Wcomb^T [256][512]
  size_t o_zsc  = alloc((size_t)N*8);                    // float2 per row
  size_t o_lsc  = alloc((size_t)N*4);                    // float per row

  hipMemsetAsync(ws + o_loss, 0, 16, stream);

  double* lossh = (double*)(ws + o_loss);
  double* lossp = lossh + 1;
  ushort* wmut = (ushort*)(ws + o_wmut);
  ushort* wr1t = (ushort*)(ws + o_wr1t);
  ushort* wr2b = (ushort*)(ws + o_wr2b);
  ushort* wct  = (ushort*)(ws + o_wct);
  float2* zsc  = (float2*)(ws + o_zsc);
  float*  lsc  = (float*)(ws + o_lsc);

  // pos branch (independent)
  pos_branch_v5<<<B, 64, 0, stream>>>(N, pos, eps_p, index, t, gpp, lossp);

  // weights + per-row scales
  const int scB = (N + NTHREADS - 1) / NTHREADS;
  prep_v5<<<320 + scB, NTHREADS, 0, stream>>>(
      (const float4*)W_r2, (ushort4*)wr2b, DH2*DH/4,
      W_mu, wmut, W_r1, wr1t,
      t, index, gph, zsc, lsc, N);

  // -Wcomb^T = -(W_r2 @ W_mu)^T
  wcomb_gemm_v5<<<dim3(DH/128, DH2/128), 256, 0, stream>>>(
      wr2b, wmut, DH, DH, DH2, wct);

  // fused h branch
  const int HB = (N + 63) / 64;
  h_branch_v5<<<HB, 256, 0, stream>>>(
      h, wmut, wr1t, wct, eps_h, zsc, lsc, N, lossh);

  finalize_v5<<<1, 64, 0, stream>>>(lossh, lossp, (float*)d_out, N, DH);
}

// Round 9
// 447.785 us; speedup vs baseline: 1.1195x; 1.1195x over previous
//
// v6 = v5 with (a) LDS trimmed to exactly 80KB (redsm removed -> 2 blocks/CU),
//      (b) B-staging bank-conflict fix: pre-swizzled global source + gsw read
//      (global_load_lds dest stays linear per rule #21).
#include <hip/hip_runtime.h>
#include <math.h>

#define NTHREADS 256
#define EPSC 1e-6f
#define NPL 3   // node slots per lane in pos branch: covers up to 192 nodes/graph

typedef short bf16x8 __attribute__((ext_vector_type(8)));
typedef float f32x4  __attribute__((ext_vector_type(4)));

#define GLDS(srcp, dstp) __builtin_amdgcn_global_load_lds( \
    (const __attribute__((address_space(1))) void*)(srcp), \
    (__attribute__((address_space(3))) void*)(dstp), 16, 0, 0)

// ---------------------------------------------------------------------------
// helpers
// ---------------------------------------------------------------------------
__device__ __forceinline__ ushort f2bf(float x) {   // RNE float->bf16
  union { float f; unsigned u; } v; v.f = x;
  unsigned r = v.u + 0x7FFFu + ((v.u >> 16) & 1u);
  return (ushort)(r >> 16);
}
__device__ __forceinline__ float bf2f(ushort x) {
  union { unsigned u; float f; } v; v.u = ((unsigned)x) << 16;
  return v.f;
}
__device__ __forceinline__ bf16x8 pack8(float4 a, float4 b) {
  bf16x8 r;
  r[0]=(short)f2bf(a.x); r[1]=(short)f2bf(a.y); r[2]=(short)f2bf(a.z); r[3]=(short)f2bf(a.w);
  r[4]=(short)f2bf(b.x); r[5]=(short)f2bf(b.y); r[6]=(short)f2bf(b.z); r[7]=(short)f2bf(b.w);
  return r;
}
__device__ __forceinline__ float tanh_fast(float x) {
  float xc = fminf(fmaxf(x, -15.f), 15.f);
  float e = __expf(2.f * xc);
  return (e - 1.f) / (e + 1.f);
}

__device__ __forceinline__ void inv3x3(const float m[9], float o[9]) {
  float a=m[0],b=m[1],c=m[2],d=m[3],e=m[4],f=m[5],g=m[6],h=m[7],i=m[8];
  float det = a*e*i + b*f*g + d*h*c - g*e*c - a*h*f - d*b*i;
  float r = 1.0f/det;
  o[0]=(e*i-f*h)*r; o[1]=(c*h-b*i)*r; o[2]=(b*f-c*e)*r;
  o[3]=(f*g-d*i)*r; o[4]=(a*i-c*g)*r; o[5]=(c*d-a*f)*r;
  o[6]=(d*h-e*g)*r; o[7]=(b*g-a*h)*r; o[8]=(a*e-b*d)*r;
}

__device__ __forceinline__ float wred(float v) {
#pragma unroll
  for (int o = 32; o > 0; o >>= 1) v += __shfl_xor(v, o, 64);
  return v;
}

// ---------------------------------------------------------------------------
// Fused pos branch: one wave per graph (verified absmax 0.0)
// ---------------------------------------------------------------------------
__global__ __launch_bounds__(64) void pos_branch_v6(
    int N, const float* __restrict__ pos, const float* __restrict__ epsp,
    const int* __restrict__ index, const float* __restrict__ t,
    const float* __restrict__ gpp, double* __restrict__ lossp)
{
  const int b = blockIdx.x;
  const int lane = threadIdx.x;

  int lo = 0, hi = N;
  while (lo < hi) { int mid = (lo + hi) >> 1; if (index[mid] < b) lo = mid + 1; else hi = mid; }
  const int start = lo;
  hi = N;
  while (lo < hi) { int mid = (lo + hi) >> 1; if (index[mid] < b + 1) lo = mid + 1; else hi = mid; }
  const int end = lo;
  const int cnt = end - start;
  const float fn = (float)cnt, rc = 1.0f / fn;

  const float tn  = t[b];
  const float a1  = 0.2f + 0.8f*tn, b1 = 0.1f*tn;
  const float omt = 1.0f - tn;
  const float sp  = log1pf(expf(gpp[0]));
  const float gp  = 0.1f + sp*tn;
  const float hg  = 0.5f*gp*gp;
  const float rgp = 1.0f/gp;
  const float pscale = 1.0f - 0.9f*omt;

  float iU[NPL][9], yv[NPL][3], wv[NPL][3], dwv[NPL][3], pv[NPL][3];
  float Vs[9] = {0}, wb[3] = {0}, dwb[3] = {0}, yb[3] = {0};
#pragma unroll
  for (int k = 0; k < NPL; ++k) {
    const int n = start + k*64 + lane;
    if (n < end) {
      const float px = pos[3*(size_t)n+0], py = pos[3*(size_t)n+1], pz = pos[3*(size_t)n+2];
      const float ex = epsp[3*(size_t)n+0], ey = epsp[3*(size_t)n+1], ez = epsp[3*(size_t)n+2];
      pv[k][0]=px; pv[k][1]=py; pv[k][2]=pz;
      const float pn = sqrtf(px*px+py*py+pz*pz) + EPSC;
      const float nx = px/pn, ny = py/pn, nz = pz/pn;
      const float nd = nx*ex + ny*ey + nz*ez;
      wv[k][0]=a1*ex + b1*nd*nx; wv[k][1]=a1*ey + b1*nd*ny; wv[k][2]=a1*ez + b1*nd*nz;
      dwv[k][0]=0.8f*ex + 0.1f*nd*nx; dwv[k][1]=0.8f*ey + 0.1f*nd*ny; dwv[k][2]=0.8f*ez + 0.1f*nd*nz;
      const float U[9] = { a1 + b1*nx*nx, b1*nx*ny,      b1*nx*nz,
                           b1*ny*nx,      a1 + b1*ny*ny, b1*ny*nz,
                           b1*nz*nx,      b1*nz*ny,      a1 + b1*nz*nz };
      inv3x3(U, iU[k]);
      yv[k][0] = iU[k][0]*ex + iU[k][3]*ey + iU[k][6]*ez;
      yv[k][1] = iU[k][1]*ex + iU[k][4]*ey + iU[k][7]*ez;
      yv[k][2] = iU[k][2]*ex + iU[k][5]*ey + iU[k][8]*ez;
#pragma unroll
      for (int j = 0; j < 9; ++j) Vs[j] += iU[k][j];
#pragma unroll
      for (int j = 0; j < 3; ++j) { wb[j]+=wv[k][j]; dwb[j]+=dwv[k][j]; yb[j]+=yv[k][j]; }
    }
  }
#pragma unroll
  for (int j = 0; j < 9; ++j) Vs[j] = wred(Vs[j]);
#pragma unroll
  for (int j = 0; j < 3; ++j) { wb[j]=wred(wb[j]); dwb[j]=wred(dwb[j]); yb[j]=wred(yb[j]); }

  float iV[9]; inv3x3(Vs, iV);
  float wm[3], dwm[3], u1[3], s1m[3];
#pragma unroll
  for (int i = 0; i < 3; ++i) { wm[i] = wb[i]*rc; dwm[i] = dwb[i]*rc; }
#pragma unroll
  for (int i = 0; i < 3; ++i) u1[i] = iV[0*3+i]*yb[0] + iV[1*3+i]*yb[1] + iV[2*3+i]*yb[2];
#pragma unroll
  for (int i = 0; i < 3; ++i) {
    const float csy = Vs[0*3+i]*u1[0] + Vs[1*3+i]*u1[1] + Vs[2*3+i]*u1[2] - fn*u1[i];
    s1m[i] = (csy - yb[i]) * rc;
  }

  float tg[NPL][3], zp[NPL][3], iU2[NPL][9], qv[NPL][3];
  float Vs2[9] = {0}, qs[3] = {0}, ps[3] = {0};
#pragma unroll
  for (int k = 0; k < NPL; ++k) {
    const int n = start + k*64 + lane;
    if (n < end) {
#pragma unroll
      for (int i = 0; i < 3; ++i) {
        const float c1 = iU[k][0*3+i]*u1[0] + iU[k][1*3+i]*u1[1] + iU[k][2*3+i]*u1[2] - u1[i];
        const float score1 = c1 - yv[k][i] - s1m[i];
        tg[k][i] = -pv[k][i] + dwv[k][i] - dwm[i] - hg*score1;
        zp[k][i] = pv[k][i]*omt + wv[k][i] - wm[i];
      }
      const float rx = 0.9f*zp[k][0], ry = 0.9f*zp[k][1], rz = 0.9f*zp[k][2];
      const float rn = sqrtf(rx*rx+ry*ry+rz*rz) + EPSC;
      const float nx = rx/rn, ny = ry/rn, nz = rz/rn;
      const float U2[9] = { a1 + b1*nx*nx, b1*nx*ny,      b1*nx*nz,
                            b1*ny*nx,      a1 + b1*ny*ny, b1*ny*nz,
                            b1*nz*nx,      b1*nz*ny,      a1 + b1*nz*nz };
      inv3x3(U2, iU2[k]);
      float prel[3];
#pragma unroll
      for (int i = 0; i < 3; ++i) prel[i] = zp[k][i]*pscale;
#pragma unroll
      for (int i = 0; i < 3; ++i)
        qv[k][i] = iU2[k][i*3+0]*prel[0] + iU2[k][i*3+1]*prel[1] + iU2[k][i*3+2]*prel[2];
#pragma unroll
      for (int j = 0; j < 9; ++j) Vs2[j] += iU2[k][j];
#pragma unroll
      for (int j = 0; j < 3; ++j) { qs[j] += qv[k][j]; ps[j] += prel[j]; }
    }
  }
#pragma unroll
  for (int j = 0; j < 9; ++j) Vs2[j] = wred(Vs2[j]);
#pragma unroll
  for (int j = 0; j < 3; ++j) { qs[j] = wred(qs[j]); ps[j] = wred(ps[j]); }

  float iV2[9]; inv3x3(Vs2, iV2);
  float cb2[3];
#pragma unroll
  for (int i = 0; i < 3; ++i)
    cb2[i] = iV2[i*3+0]*(qs[0]-ps[0]) + iV2[i*3+1]*(qs[1]-ps[1]) + iV2[i*3+2]*(qs[2]-ps[2]);

  float y2v[NPL][3], dw2v[NPL][3];
  float yb2[3] = {0}, dwb2[3] = {0};
#pragma unroll
  for (int k = 0; k < NPL; ++k) {
    const int n = start + k*64 + lane;
    if (n < end) {
      float e[3];
#pragma unroll
      for (int i = 0; i < 3; ++i)
        e[i] = qv[k][i] - (iU2[k][i*3+0]*cb2[0] + iU2[k][i*3+1]*cb2[1] + iU2[k][i*3+2]*cb2[2]);
#pragma unroll
      for (int i = 0; i < 3; ++i)
        y2v[k][i] = iU2[k][0*3+i]*e[0] + iU2[k][1*3+i]*e[1] + iU2[k][2*3+i]*e[2];
      const float rx = 0.9f*zp[k][0], ry = 0.9f*zp[k][1], rz = 0.9f*zp[k][2];
      const float rn = sqrtf(rx*rx+ry*ry+rz*rz) + EPSC;
      const float nx = rx/rn, ny = ry/rn, nz = rz/rn;
      const float nd = nx*e[0] + ny*e[1] + nz*e[2];
      dw2v[k][0] = 0.8f*e[0] + 0.1f*nd*nx;
      dw2v[k][1] = 0.8f*e[1] + 0.1f*nd*ny;
      dw2v[k][2] = 0.8f*e[2] + 0.1f*nd*nz;
#pragma unroll
      for (int j = 0; j < 3; ++j) { yb2[j] += y2v[k][j]; dwb2[j] += dw2v[k][j]; }
    }
  }
#pragma unroll
  for (int j = 0; j < 3; ++j) { yb2[j] = wred(yb2[j]); dwb2[j] = wred(dwb2[j]); }

  float u2[3], s2m[3], dw2m[3];
#pragma unroll
  for (int i = 0; i < 3; ++i) u2[i] = iV2[0*3+i]*yb2[0] + iV2[1*3+i]*yb2[1] + iV2[2*3+i]*yb2[2];
#pragma unroll
  for (int i = 0; i < 3; ++i) {
    const float csy = Vs2[0*3+i]*u2[0] + Vs2[1*3+i]*u2[1] + Vs2[2*3+i]*u2[2] - fn*u2[i];
    s2m[i] = (csy - yb2[i]) * rc;
    dw2m[i] = dwb2[i] * rc;
  }

  float acc = 0.0f;
#pragma unroll
  for (int k = 0; k < NPL; ++k) {
    const int n = start + k*64 + lane;
    if (n < end) {
#pragma unroll
      for (int i = 0; i < 3; ++i) {
        const float c2 = iU2[k][0*3+i]*u2[0] + iU2[k][1*3+i]*u2[1] + iU2[k][2*3+i]*u2[2] - u2[i];
        const float score2 = c2 - y2v[k][i] - s2m[i];
        const float dz2 = -0.9f*zp[k][i] + dw2v[k][i] - dw2m[i];
        const float apx = dz2 - hg*score2;
        const float d = (apx - tg[k][i]) * rgp;
        acc += d*d;
      }
    }
  }
  acc = wred(acc);
  if (lane == 0) atomicAdd(lossp, (double)acc);
}

// ---------------------------------------------------------------------------
// prep: W_r2 cvt (128) | W_mu^T (64) | W_r1^T (128) | row scales (rest)
// ---------------------------------------------------------------------------
__global__ __launch_bounds__(NTHREADS) void prep_v6(
    const float4* __restrict__ wr2, ushort4* __restrict__ wr2b, int n4w,
    const float* __restrict__ wmu, ushort* __restrict__ wmut,
    const float* __restrict__ wr1, ushort* __restrict__ wr1t,
    const float* __restrict__ t, const int* __restrict__ index,
    const float* __restrict__ gph,
    float2* __restrict__ zsc, float* __restrict__ lsc, int Nn)
{
  __shared__ float ts[32][33];
  const int bid = blockIdx.x;
  if (bid < 128) {
    const int i = bid*NTHREADS + threadIdx.x;
    if (i < n4w) {
      float4 v = wr2[i];
      wr2b[i] = make_ushort4(f2bf(v.x), f2bf(v.y), f2bf(v.z), f2bf(v.w));
    }
  } else if (bid < 192) {           // W_mu^T: in [256][256] -> out[n][k]
    const int vb = bid - 128;
    const int nb = (vb & 7)*32, kb = (vb >> 3)*32;
    const int tx = threadIdx.x & 31, ty = threadIdx.x >> 5;
#pragma unroll
    for (int r = 0; r < 4; ++r)
      ts[ty + r*8][tx] = wmu[(size_t)(kb + ty + r*8)*256 + nb + tx];
    __syncthreads();
#pragma unroll
    for (int r = 0; r < 4; ++r)
      wmut[(size_t)(nb + ty + r*8)*256 + kb + tx] = f2bf(ts[tx][ty + r*8]);
  } else if (bid < 320) {           // W_r1^T: in [256][512] -> out[n][k], n<512
    const int vb = bid - 192;
    const int nb = (vb & 15)*32, kb = (vb >> 4)*32;
    const int tx = threadIdx.x & 31, ty = threadIdx.x >> 5;
#pragma unroll
    for (int r = 0; r < 4; ++r)
      ts[ty + r*8][tx] = wr1[(size_t)(kb + ty + r*8)*512 + nb + tx];
    __syncthreads();
#pragma unroll
    for (int r = 0; r < 4; ++r)
      wr1t[(size_t)(nb + ty + r*8)*256 + kb + tx] = f2bf(ts[tx][ty + r*8]);
  } else {                          // per-row scales
    const int r = (bid - 320)*NTHREADS + threadIdx.x;
    if (r < Nn) {
      const float tn = t[index[r]];
      zsc[r] = make_float2(1.0f - tn, 0.1f + 0.9f*tn);
      const float sp  = log1pf(expf(gph[0]));
      const float gh  = 0.1f + sp*tn;
      const float sig = 0.1f + 0.9f*tn;
      const float fac = 1.0f + (0.9f + 0.5f*gh*gh/sig)*(1.0f - tn)/sig;
      lsc[r] = fac/gh;
    }
  }
}

// ---------------------------------------------------------------------------
// Wcomb^T = -(W_r2 @ W_mu)^T  (NEGATED). Transposed bf16 store.
// ---------------------------------------------------------------------------
__global__ __launch_bounds__(256) void wcomb_gemm_v6(
    const ushort* __restrict__ A, const ushort* __restrict__ Bt,
    int K, int Nn, int Mvalid, ushort* __restrict__ OutB)
{
  __shared__ __align__(16) ushort As[128*32];
  __shared__ __align__(16) ushort Bs[128*32];
  const int tid = threadIdx.x;
  const int row0 = blockIdx.y*128, col0 = blockIdx.x*128;
  const int wave = tid >> 6, lane = tid & 63;
  const int wm = (wave & 1)*64, wn = (wave >> 1)*64;
  const int lm = lane & 15, lq = lane >> 4;

  f32x4 acc[4][4];
#pragma unroll
  for (int i = 0; i < 4; ++i)
#pragma unroll
    for (int j = 0; j < 4; ++j) { acc[i][j][0]=0.f; acc[i][j][1]=0.f; acc[i][j][2]=0.f; acc[i][j][3]=0.f; }

  const int c0 = tid, c1 = tid + 256;
  const int r0a = c0 >> 2, k0a = (c0 & 3) << 3;
  const int r1a = c1 >> 2, k1a = (c1 & 3) << 3;

  for (int k0 = 0; k0 < K; k0 += 32) {
    __syncthreads();
    GLDS(A  + (size_t)(row0 + r0a)*K + k0 + k0a, As + c0*8);
    GLDS(A  + (size_t)(row0 + r1a)*K + k0 + k1a, As + c1*8);
    GLDS(Bt + (size_t)(col0 + r0a)*K + k0 + k0a, Bs + c0*8);
    GLDS(Bt + (size_t)(col0 + r1a)*K + k0 + k1a, Bs + c1*8);
    __syncthreads();

    bf16x8 af[4], bfr[4];
#pragma unroll
    for (int i = 0; i < 4; ++i)
      af[i] = *(const bf16x8*)&As[(wm + i*16 + lm)*32 + lq*8];
#pragma unroll
    for (int j = 0; j < 4; ++j)
      bfr[j] = *(const bf16x8*)&Bs[(wn + j*16 + lm)*32 + lq*8];
#pragma unroll
    for (int i = 0; i < 4; ++i)
#pragma unroll
      for (int j = 0; j < 4; ++j)
        acc[i][j] = __builtin_amdgcn_mfma_f32_16x16x32_bf16(af[i], bfr[j], acc[i][j], 0, 0, 0);
  }

#pragma unroll
  for (int i = 0; i < 4; ++i) {
#pragma unroll
    for (int reg = 0; reg < 4; ++reg) {
      const int r = row0 + wm + i*16 + lq*4 + reg;
#pragma unroll
      for (int j = 0; j < 4; ++j) {
        const int cc = col0 + wn + j*16 + lm;
        OutB[(size_t)cc*Mvalid + r] = f2bf(-acc[i][j][reg]);   // NEGATED, transposed
      }
    }
  }
}

// ---------------------------------------------------------------------------
// v6 fused h branch. 64 rows/block, 4 waves (column split).
//   B-staging swizzle: LDS dest LINEAR (chunk ch -> ch*16B), global source
//   granule PRE-SWIZZLED: chunk (row, slot) fetches granule slot^((row>>1)&3).
//   Read: granule gsw = lq ^ ((lm>>1)&3) -> per-phase banks 16(lm&1)+4*gsw,
//   2-way max (was 8-way).
// LDS: zs 32K + t1s 16K + bstg 32K = 81920 B exactly -> 2 blocks/CU.
// ---------------------------------------------------------------------------
__global__ __launch_bounds__(256, 2) void h_branch_v6(
    const float* __restrict__ hf, const ushort* __restrict__ wmut,
    const ushort* __restrict__ wr1t, const ushort* __restrict__ wct,
    const float* __restrict__ eps, const float2* __restrict__ zsc,
    const float* __restrict__ lsc,
    int N, double* __restrict__ lossAcc)
{
  __shared__ __align__(16) ushort zs[64*256];     // 32 KB, swizzled
  __shared__ __align__(16) ushort t1s[64*128];    // 16 KB, swizzled
  __shared__ __align__(16) ushort bstg[4*4096];   // 32 KB: per-wave 2x4KB bufs

  const int wave = threadIdx.x >> 6, lane = threadIdx.x & 63;
  const int row0 = blockIdx.x * 64;
  const int lm = lane & 15, lq = lane >> 4;
  const int wn  = wave * 64;    // col base within 256 (GEMM1 / loss)
  const int wn2 = wave * 32;    // col base within 128 (T1 chunk)
  ushort* const bsw = bstg + wave*4096;   // [2][2048] ushorts
  const int gsw8 = (lq ^ ((lm >> 1) & 3)) * 8;   // swizzled B-read granule

  // row indices for this thread's A-fragments (clamped; masked in loss)
  int arow[4];
#pragma unroll
  for (int i = 0; i < 4; ++i) {
    int r = row0 + i*16 + lm; if (r >= N) r = N - 1;
    arow[i] = r;
  }

  // ---- GEMM1 prologue: A(0) 8 f32x4 loads + B(0) 4 GLDS (12 in flight) ----
  float4 aCur[8], aNxt[8];
#pragma unroll
  for (int i = 0; i < 4; ++i) {
    const float4* p = (const float4*)(hf + (size_t)arow[i]*256 + lq*8);
    aCur[2*i] = p[0]; aCur[2*i+1] = p[1];
  }
#pragma unroll
  for (int c = 0; c < 4; ++c) {
    const int ch = c*64 + lane;
    const int rw = ch >> 2, gs = (ch & 3) ^ ((rw >> 1) & 3);
    GLDS(wmut + (size_t)(wn + rw)*256 + gs*8, bsw + ch*8);
  }

  f32x4 acc[4][4];
#pragma unroll
  for (int i = 0; i < 4; ++i)
#pragma unroll
    for (int j = 0; j < 4; ++j) { acc[i][j][0]=0.f; acc[i][j][1]=0.f; acc[i][j][2]=0.f; acc[i][j][3]=0.f; }

#pragma unroll
  for (int k = 0; k < 8; ++k) {
    if (k < 7) {
#pragma unroll
      for (int i = 0; i < 4; ++i) {
        const float4* p = (const float4*)(hf + (size_t)arow[i]*256 + (k+1)*32 + lq*8);
        aNxt[2*i] = p[0]; aNxt[2*i+1] = p[1];
      }
#pragma unroll
      for (int c = 0; c < 4; ++c) {
        const int ch = c*64 + lane;
        const int rw = ch >> 2, gs = (ch & 3) ^ ((rw >> 1) & 3);
        GLDS(wmut + (size_t)(wn + rw)*256 + (k+1)*32 + gs*8,
             bsw + ((k+1)&1)*2048 + ch*8);
      }
      asm volatile("s_waitcnt vmcnt(12)" ::: "memory");   // A(k+1)+B(k+1) fly
    } else {
      asm volatile("s_waitcnt vmcnt(0)" ::: "memory");
    }
    __builtin_amdgcn_sched_barrier(0);

    const ushort* cb = bsw + (k&1)*2048;
    bf16x8 a_[4], b_[4];
#pragma unroll
    for (int i = 0; i < 4; ++i) a_[i] = pack8(aCur[2*i], aCur[2*i+1]);
#pragma unroll
    for (int j = 0; j < 4; ++j)
      b_[j] = *(const bf16x8*)&cb[(j*16 + lm)*32 + gsw8];
#pragma unroll
    for (int i = 0; i < 4; ++i)
#pragma unroll
      for (int j = 0; j < 4; ++j)
        acc[i][j] = __builtin_amdgcn_mfma_f32_16x16x32_bf16(a_[i], b_[j], acc[i][j], 0, 0, 0);

    if (k < 7) {
#pragma unroll
      for (int q = 0; q < 8; ++q) aCur[q] = aNxt[q];
    }
  }

  // early-stage chunk0 GEMM2 B0 (own 32-col slice of W_r1^T)
#pragma unroll
  for (int c = 0; c < 2; ++c) {
    const int ch = c*64 + lane;
    const int rw = ch >> 2, gs = (ch & 3) ^ ((rw >> 1) & 3);
    GLDS(wr1t + (size_t)(wn2 + rw)*256 + gs*8, bsw + ch*8);
  }

  // ---- epilogue 1: z_h -> swizzled LDS (acc keeps Hm in f32) ----
#pragma unroll
  for (int i = 0; i < 4; ++i) {
#pragma unroll
    for (int reg = 0; reg < 4; ++reg) {
      const int rb = i*16 + lq*4 + reg;
      const int r = row0 + rb;
      const int rcl = (r < N) ? r : (N - 1);
      const float2 sz = zsc[rcl];
#pragma unroll
      for (int j = 0; j < 4; ++j) {
        const int cc = wn + j*16 + lm;
        const float z = acc[i][j][reg]*sz.x + sz.y*eps[(size_t)rcl*256 + cc];
        zs[rb*256 + (cc ^ ((rb & 7) << 3))] = f2bf(z);
      }
    }
  }
  __syncthreads();   // zs visible (drains in-flight staging too)

  // ---- chunk loop ----
  for (int c2 = 0; c2 < 4; ++c2) {
    f32x4 acct[4][2];
#pragma unroll
    for (int i = 0; i < 4; ++i)
#pragma unroll
      for (int j = 0; j < 2; ++j) { acct[i][j][0]=0.f; acct[i][j][1]=0.f; acct[i][j][2]=0.f; acct[i][j][3]=0.f; }

#pragma unroll
    for (int k = 0; k < 8; ++k) {
      if (k < 7) {
#pragma unroll
        for (int c = 0; c < 2; ++c) {
          const int ch = c*64 + lane;
          const int rw = ch >> 2, gs = (ch & 3) ^ ((rw >> 1) & 3);
          GLDS(wr1t + (size_t)(c2*128 + wn2 + rw)*256 + (k+1)*32 + gs*8,
               bsw + ((k+1)&1)*2048 + ch*8);
        }
        asm volatile("s_waitcnt vmcnt(2)" ::: "memory");
      } else {
        asm volatile("s_waitcnt vmcnt(0)" ::: "memory");
      }
      __builtin_amdgcn_sched_barrier(0);

      const ushort* cb = bsw + (k&1)*2048;
      bf16x8 az[4], b_[2];
#pragma unroll
      for (int i = 0; i < 4; ++i) {
        const int r = i*16 + lm;
        const int c = k*32 + lq*8;
        az[i] = *(const bf16x8*)&zs[r*256 + (c ^ ((r & 7) << 3))];
      }
#pragma unroll
      for (int j = 0; j < 2; ++j)
        b_[j] = *(const bf16x8*)&cb[(j*16 + lm)*32 + gsw8];
#pragma unroll
      for (int i = 0; i < 4; ++i)
#pragma unroll
        for (int j = 0; j < 2; ++j)
          acct[i][j] = __builtin_amdgcn_mfma_f32_16x16x32_bf16(az[i], b_[j], acct[i][j], 0, 0, 0);
    }

    // early-stage GEMM3 B0 (own 64-col slice of -Wcomb^T, this chunk)
#pragma unroll
    for (int c = 0; c < 4; ++c) {
      const int ch = c*64 + lane;
      const int rw = ch >> 2, gs = (ch & 3) ^ ((rw >> 1) & 3);
      GLDS(wct + (size_t)(wn + rw)*512 + c2*128 + gs*8, bsw + ch*8);
    }
    __syncthreads();   // barrier_A: all waves past prev-chunk t1s reads

#pragma unroll
    for (int i = 0; i < 4; ++i)
#pragma unroll
      for (int j = 0; j < 2; ++j)
#pragma unroll
        for (int reg = 0; reg < 4; ++reg) {
          const int rb = i*16 + lq*4 + reg;
          const int c = wn2 + j*16 + lm;
          t1s[rb*128 + (c ^ ((rb & 7) << 3))] = f2bf(tanh_fast(acct[i][j][reg]));
        }
    __syncthreads();   // barrier_B: t1s visible

#pragma unroll
    for (int k = 0; k < 4; ++k) {
      if (k < 3) {
#pragma unroll
        for (int c = 0; c < 4; ++c) {
          const int ch = c*64 + lane;
          const int rw = ch >> 2, gs = (ch & 3) ^ ((rw >> 1) & 3);
          GLDS(wct + (size_t)(wn + rw)*512 + c2*128 + (k+1)*32 + gs*8,
               bsw + ((k+1)&1)*2048 + ch*8);
        }
        asm volatile("s_waitcnt vmcnt(4)" ::: "memory");
      } else {
        asm volatile("s_waitcnt vmcnt(0)" ::: "memory");
      }
      __builtin_amdgcn_sched_barrier(0);

      const ushort* cb = bsw + (k&1)*2048;
      bf16x8 at[4], b_[4];
#pragma unroll
      for (int i = 0; i < 4; ++i) {
        const int r = i*16 + lm;
        const int c = k*32 + lq*8;
        at[i] = *(const bf16x8*)&t1s[r*128 + (c ^ ((r & 7) << 3))];
      }
#pragma unroll
      for (int j = 0; j < 4; ++j)
        b_[j] = *(const bf16x8*)&cb[(j*16 + lm)*32 + gsw8];
#pragma unroll
      for (int i = 0; i < 4; ++i)
#pragma unroll
        for (int j = 0; j < 4; ++j)
          acc[i][j] = __builtin_amdgcn_mfma_f32_16x16x32_bf16(at[i], b_[j], acc[i][j], 0, 0, 0);
    }

    if (c2 < 3) {   // early-stage next chunk's GEMM2 B0
#pragma unroll
      for (int c = 0; c < 2; ++c) {
        const int ch = c*64 + lane;
        const int rw = ch >> 2, gs = (ch & 3) ^ ((rw >> 1) & 3);
        GLDS(wr1t + (size_t)((c2+1)*128 + wn2 + rw)*256 + gs*8, bsw + ch*8);
      }
    }
  }

  // ---- loss epilogue: acc already = Hm - T1@Wcomb;  d = acc * lsc[r] ----
  float local = 0.f;
#pragma unroll
  for (int i = 0; i < 4; ++i) {
#pragma unroll
    for (int reg = 0; reg < 4; ++reg) {
      const int r = row0 + i*16 + lq*4 + reg;
      if (r < N) {
        const float sc = lsc[r];
#pragma unroll
        for (int j = 0; j < 4; ++j) {
          const float d = acc[i][j][reg] * sc;
          local += d*d;
        }
      }
    }
  }
  double dv = (double)local;
#pragma unroll
  for (int off = 32; off > 0; off >>= 1) dv += __shfl_down(dv, off, 64);
  if (lane == 0) atomicAdd(lossAcc, dv);   // 4 atomics/block (v2-verified)
}

__global__ void finalize_v6(const double* lossh, const double* lossp,
                            float* out, int N, int DH)
{
  if (threadIdx.x == 0) {
    out[0] = (float)(lossh[0] / ((double)N * (double)DH));
    out[1] = (float)(lossp[0] / ((double)N * 3.0));
  }
}

// ---------------------------------------------------------------------------
extern "C" void kernel_launch(void* const* d_in, const int* in_sizes, int n_in,
                              void* d_out, int out_size, void* d_ws, size_t ws_size,
                              hipStream_t stream) {
  const float* t      = (const float*)d_in[0];
  const float* h      = (const float*)d_in[1];
  const float* pos    = (const float*)d_in[2];
  const float* eps_h  = (const float*)d_in[3];
  const float* eps_p  = (const float*)d_in[4];
  const float* gph    = (const float*)d_in[5];
  const float* gpp    = (const float*)d_in[6];
  const float* W_mu   = (const float*)d_in[7];
  const float* W_r1   = (const float*)d_in[8];
  const float* W_r2   = (const float*)d_in[9];
  const int*   index  = (const int*)d_in[10];
  const int B = in_sizes[0];
  const int N = in_sizes[10];
  const int DH = 256, DH2 = 512;

  char* ws = (char*)d_ws;
  size_t off = 0;
  auto alloc = [&](size_t nbytes) { size_t o = off; off += (nbytes + 255) & ~(size_t)255; return o; };

  size_t o_loss = alloc(16);                             // 2 doubles (zeroed)
  size_t o_wmut = alloc((size_t)DH*DH*2);                // W_mu^T  [256][256]
  size_t o_wr1t = alloc((size_t)DH2*DH*2);               // W_r1^T  [512][256]
  size_t o_wr2b = alloc((size_t)DH2*DH*2);               // W_r2 bf16 [512][256]
  size_t o_wct  = alloc((size_t)DH*DH2*2);               // -Wcomb^T [256][512]
  size_t o_zsc  = alloc((size_t)N*8);                    // float2 per row
  size_t o_lsc  = alloc((size_t)N*4);                    // float per row

  hipMemsetAsync(ws + o_loss, 0, 16, stream);

  double* lossh = (double*)(ws + o_loss);
  double* lossp = lossh + 1;
  ushort* wmut = (ushort*)(ws + o_wmut);
  ushort* wr1t = (ushort*)(ws + o_wr1t);
  ushort* wr2b = (ushort*)(ws + o_wr2b);
  ushort* wct  = (ushort*)(ws + o_wct);
  float2* zsc  = (float2*)(ws + o_zsc);
  float*  lsc  = (float*)(ws + o_lsc);

  // pos branch (independent)
  pos_branch_v6<<<B, 64, 0, stream>>>(N, pos, eps_p, index, t, gpp, lossp);

  // weights + per-row scales
  const int scB = (N + NTHREADS - 1) / NTHREADS;
  prep_v6<<<320 + scB, NTHREADS, 0, stream>>>(
      (const float4*)W_r2, (ushort4*)wr2b, DH2*DH/4,
      W_mu, wmut, W_r1, wr1t,
      t, index, gph, zsc, lsc, N);

  // -Wcomb^T = -(W_r2 @ W_mu)^T
  wcomb_gemm_v6<<<dim3(DH/128, DH2/128), 256, 0, stream>>>(
      wr2b, wmut, DH, DH, DH2, wct);

  // fused h branch
  const int HB = (N + 63) / 64;
  h_branch_v6<<<HB, 256, 0, stream>>>(
      h, wmut, wr1t, wct, eps_h, zsc, lsc, N, lossh);

  finalize_v6<<<1, 64, 0, stream>>>(lossh, lossp, (float*)d_out, N, DH);
}